// Round 1
// baseline (142.930 us; speedup 1.0000x reference)
//
#include <hip/hip_runtime.h>

#define N_TOK 8192

typedef _Float16 f16x8 __attribute__((ext_vector_type(8)));
typedef _Float16 f16x4 __attribute__((ext_vector_type(4)));
typedef float    f32x4 __attribute__((ext_vector_type(4)));

__device__ __forceinline__ f32x4 mfma_k32(f16x8 a, f16x8 b, f32x4 c) {
  return __builtin_amdgcn_mfma_f32_16x16x32_f16(a, b, c, 0, 0, 0);
}
// Legacy K=16 MFMA: B-frag layout B[k=quad*4+b][col=l15] matches the K=32
// C layout (rows quad*4+r in regs) exactly -> P feeds PV with NO transpose.
__device__ __forceinline__ f32x4 mfma_k16(f16x4 a, f16x4 b, f32x4 c) {
  return __builtin_amdgcn_mfma_f32_16x16x16f16(a, b, c, 0, 0, 0);
}

// QSCALE^2 = log2(e)/sqrt(32); fold softmax scale + ln->log2 into q so
// s2[n,m] = qe_n . qe_m is directly the exp2 exponent.
#define QSCALE 0.50500977f

// ---------------------------------------------------------------------------
// Kernel A: qe[n][32] = fp16((W x + bias) * QSCALE); vh = fp16(x)
// ---------------------------------------------------------------------------
__global__ __launch_bounds__(256) void prep_kernel(
    const float* __restrict__ x, const float* __restrict__ W,
    const float* __restrict__ bias, _Float16* __restrict__ qe,
    _Float16* __restrict__ vh) {
  int blk = blockIdx.x, t = threadIdx.x;
  if (blk < 1024) {
    __shared__ float Wl[32 * 65];  // pad 65: lane-distinct banks
    for (int i = t; i < 2048; i += 256) Wl[(i >> 6) * 65 + (i & 63)] = W[i];
    __syncthreads();
    int g = blk * 256 + t;
    int o = g & 31, n = g >> 5;
    float acc0 = bias[o], acc1 = 0.f;
#pragma unroll
    for (int c = 0; c < 32; ++c) {
      acc0 = fmaf(Wl[o * 65 + c], x[c * N_TOK + n], acc0);
      acc1 = fmaf(Wl[o * 65 + 32 + c], x[(32 + c) * N_TOK + n], acc1);
    }
    qe[n * 32 + o] = (_Float16)((acc0 + acc1) * QSCALE);
  } else {
    int i4 = (blk - 1024) * 256 + t;  // float4 index, 512 blocks cover 512K elts
    f32x4 v = ((const f32x4*)x)[i4];
    f16x4 h;
#pragma unroll
    for (int j = 0; j < 4; ++j) h[j] = (_Float16)v[j];
    *(f16x4*)(vh + i4 * 4) = h;
  }
}

// ---------------------------------------------------------------------------
// Kernel B (pass 1): Bn[n] = log2( sum_m exp2(qe_n . qe_m) )
// 256 blocks x 1024 thr (16 waves): block = 32 rows, waves split the 8192
// m-columns 16 ways (512 each) -> 16 waves/CU instead of 8, half the chain
// length per wave.
// ---------------------------------------------------------------------------
__global__ __launch_bounds__(1024) void pass1_kernel(
    const _Float16* __restrict__ qe, float* __restrict__ Bn) {
  __shared__ float Lp[16][32];
  int t = threadIdx.x;
  int w = t >> 6, lane = t & 63, quad = lane >> 4, l15 = lane & 15;
  int n0 = blockIdx.x * 32;
  f16x8 af0 = *(const f16x8*)(qe + (n0 + l15) * 32 + quad * 8);
  f16x8 af1 = *(const f16x8*)(qe + (n0 + 16 + l15) * 32 + quad * 8);
  f32x4 sums0 = {0.f, 0.f, 0.f, 0.f}, sums1 = {0.f, 0.f, 0.f, 0.f};
  for (int mt = 0; mt < 32; ++mt) {
    int m0 = w * 512 + mt * 16;
    f16x8 bf = *(const f16x8*)(qe + (m0 + l15) * 32 + quad * 8);
    f32x4 zero = {0.f, 0.f, 0.f, 0.f};
    f32x4 s0 = mfma_k32(af0, bf, zero);  // rows n0+quad*4+r, col m0+l15
    f32x4 s1 = mfma_k32(af1, bf, zero);  // rows n0+16+quad*4+r
#pragma unroll
    for (int r = 0; r < 4; ++r) {
      sums0[r] += __builtin_amdgcn_exp2f(s0[r]);
      sums1[r] += __builtin_amdgcn_exp2f(s1[r]);
    }
  }
  // reduce across the 16 m-columns (l15 bits = lane bits 0..3)
#pragma unroll
  for (int r = 0; r < 4; ++r) {
#pragma unroll
    for (int mask = 1; mask < 16; mask <<= 1) {
      sums0[r] += __shfl_xor(sums0[r], mask, 64);
      sums1[r] += __shfl_xor(sums1[r], mask, 64);
    }
  }
  if (l15 == 0) {
    *(f32x4*)&Lp[w][quad * 4] = sums0;
    *(f32x4*)&Lp[w][16 + quad * 4] = sums1;
  }
  __syncthreads();
  if (t < 32) {
    float L = 0.f;
#pragma unroll
    for (int ww = 0; ww < 16; ++ww) L += Lp[ww][t];
    Bn[n0 + t] = __builtin_amdgcn_logf(L);  // v_log_f32 = log2
  }
}

// ---------------------------------------------------------------------------
// Kernel C (pass 2): out[c,m] = sum_n vh[c,n] * exp2(qe_n.qe_m - Bn[n]) + x
// 256 blocks x 1024 thr (16 waves). Block = 32 m-cols, all 64 c.
// Waves split n 16 ways (512 each), chunk = 16 n.
// NO LDS / NO waits in the main loop: the exp2'd S quadrant (rows quad*4+r
// in regs, col l15 in lanes), packed to f16, IS the B-fragment of the K=16
// MFMA (B[k=quad*4+b][col=l15]) -> PV consumes P in-register.
// ---------------------------------------------------------------------------
__global__ __launch_bounds__(1024) void pass2_kernel(
    const _Float16* __restrict__ qe, const _Float16* __restrict__ vh,
    const float* __restrict__ Bn, const float* __restrict__ x,
    float* __restrict__ out) {
  __shared__ float Ot[8 * 64 * 33];  // combine: [8 sets][64 c][33]
  int t = threadIdx.x;
  int w = t >> 6, lane = t & 63, quad = lane >> 4, l15 = lane & 15;
  int m0 = blockIdx.x * 32;

  // B frags for the S matmul: cols m0..m0+31 (fixed for whole kernel)
  f16x8 bm0 = *(const f16x8*)(qe + (m0 + l15) * 32 + quad * 8);
  f16x8 bm1 = *(const f16x8*)(qe + (m0 + 16 + l15) * 32 + quad * 8);

  f32x4 acc[4][2];
#pragma unroll
  for (int ct = 0; ct < 4; ++ct)
#pragma unroll
    for (int mt = 0; mt < 2; ++mt) acc[ct][mt] = f32x4{0.f, 0.f, 0.f, 0.f};

  for (int ch = 0; ch < 32; ++ch) {
    int nb = w * 512 + ch * 16;
    // Issue all global loads up front; they overlap the S-MFMA + exp2 below.
    f16x8 a = *(const f16x8*)(qe + (nb + l15) * 32 + quad * 8);
    f32x4 Bq = *(const f32x4*)(Bn + nb + quad * 4);
    f16x4 av[4];
#pragma unroll
    for (int ct = 0; ct < 4; ++ct)
      av[ct] = *(const f16x4*)(vh + (ct * 16 + l15) * N_TOK + nb + quad * 4);

    f32x4 zero = {0.f, 0.f, 0.f, 0.f};
    f32x4 s0 = mfma_k32(a, bm0, zero);  // rows nb+quad*4+r, col m0+l15
    f32x4 s1 = mfma_k32(a, bm1, zero);  // rows nb+quad*4+r, col m0+16+l15
    f16x4 p0, p1;
#pragma unroll
    for (int r = 0; r < 4; ++r) {
      p0[r] = (_Float16)__builtin_amdgcn_exp2f(s0[r] - Bq[r]);
      p1[r] = (_Float16)__builtin_amdgcn_exp2f(s1[r] - Bq[r]);
    }
    // PV: A = vh rows c (row=l15, k=quad*4+b), B = p (k=quad*4+b, col=l15).
#pragma unroll
    for (int ct = 0; ct < 4; ++ct) {
      acc[ct][0] = mfma_k16(av[ct], p0, acc[ct][0]);
      acc[ct][1] = mfma_k16(av[ct], p1, acc[ct][1]);
    }
  }

  // Combine partials across the 16 n-segments (staged: 16 -> 8 -> 1).
  if (w < 8) {
#pragma unroll
    for (int ct = 0; ct < 4; ++ct)
#pragma unroll
      for (int mt = 0; mt < 2; ++mt)
#pragma unroll
        for (int r = 0; r < 4; ++r)
          Ot[(w * 64 + ct * 16 + quad * 4 + r) * 33 + mt * 16 + l15] =
              acc[ct][mt][r];
  }
  __syncthreads();
  if (w >= 8) {
#pragma unroll
    for (int ct = 0; ct < 4; ++ct)
#pragma unroll
      for (int mt = 0; mt < 2; ++mt)
#pragma unroll
        for (int r = 0; r < 4; ++r)
          Ot[((w - 8) * 64 + ct * 16 + quad * 4 + r) * 33 + mt * 16 + l15] +=
              acc[ct][mt][r];
  }
  __syncthreads();
  // 2048 outputs, 1024 threads -> 2 each; m consecutive across lanes.
  for (int idx = t; idx < 2048; idx += 1024) {
    int cc = idx >> 5, m = idx & 31;
    float v = 0.f;
#pragma unroll
    for (int s = 0; s < 8; ++s) v += Ot[(s * 64 + cc) * 33 + m];
    out[cc * N_TOK + m0 + m] = v + x[cc * N_TOK + m0 + m];
  }
}

// ---------------------------------------------------------------------------
extern "C" void kernel_launch(void* const* d_in, const int* in_sizes, int n_in,
                              void* d_out, int out_size, void* d_ws,
                              size_t ws_size, hipStream_t stream) {
  const float* x = (const float*)d_in[0];     // [64][8192]
  const float* W = (const float*)d_in[1];     // [32][64]
  const float* bias = (const float*)d_in[2];  // [32]
  float* out = (float*)d_out;                 // [64][8192]

  char* ws = (char*)d_ws;
  _Float16* qe = (_Float16*)ws;                 // 8192*32*2 = 512 KB
  _Float16* vh = (_Float16*)(ws + 524288);      // 64*8192*2 = 1 MB
  float* Bn = (float*)(ws + 524288 + 1048576);  // 8192*4 = 32 KB

  prep_kernel<<<1536, 256, 0, stream>>>(x, W, bias, qe, vh);
  pass1_kernel<<<256, 1024, 0, stream>>>(qe, Bn);
  pass2_kernel<<<256, 1024, 0, stream>>>(qe, vh, Bn, x, out);
}

// Round 3
// 101.982 us; speedup vs baseline: 1.4015x; 1.4015x over previous
//
#include <hip/hip_runtime.h>

#define N_TOK 8192

typedef _Float16 f16x8 __attribute__((ext_vector_type(8)));
typedef _Float16 f16x4 __attribute__((ext_vector_type(4)));
typedef float    f32x4 __attribute__((ext_vector_type(4)));

__device__ __forceinline__ f32x4 mfma_k32(f16x8 a, f16x8 b, f32x4 c) {
  return __builtin_amdgcn_mfma_f32_16x16x32_f16(a, b, c, 0, 0, 0);
}
// Legacy K=16 MFMA: B-frag layout B[k=quad*4+b][col=l15] matches the K=32
// C layout (rows quad*4+r in regs) exactly -> P feeds PV with NO transpose.
__device__ __forceinline__ f32x4 mfma_k16(f16x4 a, f16x4 b, f32x4 c) {
  return __builtin_amdgcn_mfma_f32_16x16x16f16(a, b, c, 0, 0, 0);
}

// QSCALE^2 = log2(e)/sqrt(32); fold softmax scale + ln->log2 into q so
// s2[n,m] = qe_n . qe_m is directly the exp2 exponent.
#define QSCALE 0.50500977f

// ---------------------------------------------------------------------------
// Kernel A: qe[n][32] = fp16((W x + bias) * QSCALE)
//           vht = fp16(x) in BLOCKED layout: vht[nblk][c][inner32] where
//           inner order for n_local k*4..k*4+3 (k=0..7) sits at q*8+h*4
//           (q=k&3, h=k>>2). A lane's f16x8 at inner q*8 then holds
//           n_local {q*4..+3, 16+q*4..+3} = the two K=16 PV A-frags,
//           and a wave's 4 av loads cover a fully-contiguous 4KB tile.
// ---------------------------------------------------------------------------
__global__ __launch_bounds__(256) void prep_kernel(
    const float* __restrict__ x, const float* __restrict__ W,
    const float* __restrict__ bias, _Float16* __restrict__ qe,
    _Float16* __restrict__ vht) {
  int blk = blockIdx.x, t = threadIdx.x;
  if (blk < 1024) {
    __shared__ float Wl[32 * 65];  // pad 65: lane-distinct banks
    for (int i = t; i < 2048; i += 256) Wl[(i >> 6) * 65 + (i & 63)] = W[i];
    __syncthreads();
    int g = blk * 256 + t;
    int o = g & 31, n = g >> 5;
    float acc0 = bias[o], acc1 = 0.f;
#pragma unroll
    for (int c = 0; c < 32; ++c) {
      acc0 = fmaf(Wl[o * 65 + c], x[c * N_TOK + n], acc0);
      acc1 = fmaf(Wl[o * 65 + 32 + c], x[(32 + c) * N_TOK + n], acc1);
    }
    qe[n * 32 + o] = (_Float16)((acc0 + acc1) * QSCALE);
  } else {
    int i = (blk - 1024) * 256 + t;  // float4 index; 512 blocks cover 128K f4
    f32x4 v = ((const f32x4*)x)[i];  // x[c][n4*4..+3], c=i>>11, n4=i&2047
    f16x4 hv;
#pragma unroll
    for (int j = 0; j < 4; ++j) hv[j] = (_Float16)v[j];
    int c = i >> 11, n4 = i & 2047;
    int nblk = n4 >> 3, k = n4 & 7, q = k & 3, h = k >> 2;
    *(f16x4*)(vht + nblk * 2048 + c * 32 + q * 8 + h * 4) = hv;
  }
}

// ---------------------------------------------------------------------------
// Kernel B (pass 1): Bn[n] = log2( sum_m exp2(qe_n . qe_m) )
// 256 blocks x 1024 thr (16 waves): block = 32 rows, waves split the 8192
// m-columns 16 ways. 32 m per iter -> 4 independent MFMA chains (ILP).
// ---------------------------------------------------------------------------
__global__ __launch_bounds__(1024) void pass1_kernel(
    const _Float16* __restrict__ qe, float* __restrict__ Bn) {
  __shared__ float Lp[16][32];
  int t = threadIdx.x;
  int w = t >> 6, lane = t & 63, quad = lane >> 4, l15 = lane & 15;
  int n0 = blockIdx.x * 32;
  f16x8 af0 = *(const f16x8*)(qe + (n0 + l15) * 32 + quad * 8);
  f16x8 af1 = *(const f16x8*)(qe + (n0 + 16 + l15) * 32 + quad * 8);
  f32x4 sums0 = {0.f, 0.f, 0.f, 0.f}, sums1 = {0.f, 0.f, 0.f, 0.f};
  for (int mt = 0; mt < 16; ++mt) {
    int m0 = w * 512 + mt * 32;
    f16x8 bf0 = *(const f16x8*)(qe + (m0 + l15) * 32 + quad * 8);
    f16x8 bf1 = *(const f16x8*)(qe + (m0 + 16 + l15) * 32 + quad * 8);
    f32x4 zero = {0.f, 0.f, 0.f, 0.f};
    f32x4 s00 = mfma_k32(af0, bf0, zero);  // rows n0+quad*4+r, col m0+l15
    f32x4 s01 = mfma_k32(af0, bf1, zero);  // rows n0+quad*4+r, col m0+16+l15
    f32x4 s10 = mfma_k32(af1, bf0, zero);  // rows n0+16+quad*4+r
    f32x4 s11 = mfma_k32(af1, bf1, zero);
#pragma unroll
    for (int r = 0; r < 4; ++r) {
      sums0[r] += __builtin_amdgcn_exp2f(s00[r]) + __builtin_amdgcn_exp2f(s01[r]);
      sums1[r] += __builtin_amdgcn_exp2f(s10[r]) + __builtin_amdgcn_exp2f(s11[r]);
    }
  }
  // reduce across the 16 m-columns (l15 bits = lane bits 0..3)
#pragma unroll
  for (int r = 0; r < 4; ++r) {
#pragma unroll
    for (int mask = 1; mask < 16; mask <<= 1) {
      sums0[r] += __shfl_xor(sums0[r], mask, 64);
      sums1[r] += __shfl_xor(sums1[r], mask, 64);
    }
  }
  if (l15 == 0) {
    *(f32x4*)&Lp[w][quad * 4] = sums0;
    *(f32x4*)&Lp[w][16 + quad * 4] = sums1;
  }
  __syncthreads();
  if (t < 32) {
    float L = 0.f;
#pragma unroll
    for (int ww = 0; ww < 16; ++ww) L += Lp[ww][t];
    Bn[n0 + t] = __builtin_amdgcn_logf(L);  // v_log_f32 = log2
  }
}

// ---------------------------------------------------------------------------
// Kernel C (pass 2): out[c,m] = sum_n vh[c,n] * exp2(qe_n.qe_m - Bn[n]) + x
// 256 blocks x 1024 thr (16 waves). Block = 32 m-cols, all 64 c.
// Waves split n 16 ways (512 each), chunk = 32 n, double-buffered prefetch.
// NO LDS / NO barriers in the main loop; P feeds PV in-register via K=16
// MFMA; all global loads are 16B/lane DENSE (vht blocked layout).
// ---------------------------------------------------------------------------
__global__ __launch_bounds__(1024) void pass2_kernel(
    const _Float16* __restrict__ qe, const _Float16* __restrict__ vht,
    const float* __restrict__ Bn, const float* __restrict__ x,
    float* __restrict__ out) {
  __shared__ float Ot[8 * 64 * 33];  // combine: [8 sets][64 c][33]
  int t = threadIdx.x;
  int w = t >> 6, lane = t & 63, quad = lane >> 4, l15 = lane & 15;
  int m0 = blockIdx.x * 32;

  // B frags for the S matmul: cols m0..m0+31 (fixed for whole kernel)
  f16x8 bm0 = *(const f16x8*)(qe + (m0 + l15) * 32 + quad * 8);
  f16x8 bm1 = *(const f16x8*)(qe + (m0 + 16 + l15) * 32 + quad * 8);

  f32x4 acc[4][2];
#pragma unroll
  for (int ct = 0; ct < 4; ++ct)
#pragma unroll
    for (int mt = 0; mt < 2; ++mt) acc[ct][mt] = f32x4{0.f, 0.f, 0.f, 0.f};

  // Double-buffered chunk operands (register sets A/B, all static names).
  f16x8 anA0, anA1, avA[4];
  f32x4 BqA0, BqA1;
  f16x8 anB0, anB1, avB[4];
  f32x4 BqB0, BqB1;

#define LOADCH(SUF, NB)                                                     \
  do {                                                                      \
    int nb_ = (NB);                                                         \
    an##SUF##0 = *(const f16x8*)(qe + (nb_ + l15) * 32 + quad * 8);         \
    an##SUF##1 = *(const f16x8*)(qe + (nb_ + 16 + l15) * 32 + quad * 8);    \
    Bq##SUF##0 = *(const f32x4*)(Bn + nb_ + quad * 4);                      \
    Bq##SUF##1 = *(const f32x4*)(Bn + nb_ + 16 + quad * 4);                 \
    const _Float16* vb_ = vht + (nb_ >> 5) * 2048 + l15 * 32 + quad * 8;    \
    _Pragma("unroll") for (int ct = 0; ct < 4; ++ct) av##SUF[ct] =          \
        *(const f16x8*)(vb_ + ct * 512);                                    \
  } while (0)

#define COMPUTECH(SUF)                                                      \
  do {                                                                      \
    f32x4 zero = {0.f, 0.f, 0.f, 0.f};                                      \
    f32x4 s00 = mfma_k32(an##SUF##0, bm0, zero); /* n=quad*4+r, m=l15 */    \
    f32x4 s01 = mfma_k32(an##SUF##0, bm1, zero); /* m=16+l15 */             \
    f32x4 s10 = mfma_k32(an##SUF##1, bm0, zero); /* n=16+quad*4+r */        \
    f32x4 s11 = mfma_k32(an##SUF##1, bm1, zero);                            \
    f16x4 p00, p01, p10, p11;                                               \
    _Pragma("unroll") for (int r = 0; r < 4; ++r) {                         \
      p00[r] = (_Float16)__builtin_amdgcn_exp2f(s00[r] - Bq##SUF##0[r]);    \
      p01[r] = (_Float16)__builtin_amdgcn_exp2f(s01[r] - Bq##SUF##0[r]);    \
      p10[r] = (_Float16)__builtin_amdgcn_exp2f(s10[r] - Bq##SUF##1[r]);    \
      p11[r] = (_Float16)__builtin_amdgcn_exp2f(s11[r] - Bq##SUF##1[r]);    \
    }                                                                       \
    _Pragma("unroll") for (int ct = 0; ct < 4; ++ct) {                      \
      f16x4 lo, hi;                                                         \
      _Pragma("unroll") for (int j = 0; j < 4; ++j) {                       \
        lo[j] = av##SUF[ct][j];                                             \
        hi[j] = av##SUF[ct][j + 4];                                         \
      }                                                                     \
      acc[ct][0] = mfma_k16(lo, p00, acc[ct][0]);                           \
      acc[ct][0] = mfma_k16(hi, p10, acc[ct][0]);                           \
      acc[ct][1] = mfma_k16(lo, p01, acc[ct][1]);                           \
      acc[ct][1] = mfma_k16(hi, p11, acc[ct][1]);                           \
    }                                                                       \
  } while (0)

  int nbase = w * 512;
  LOADCH(A, nbase);
  for (int ch2 = 0; ch2 < 8; ++ch2) {
    int nb = nbase + ch2 * 64;
    LOADCH(B, nb + 32);
    COMPUTECH(A);
    if (ch2 < 7) LOADCH(A, nb + 64);
    COMPUTECH(B);
  }
#undef LOADCH
#undef COMPUTECH

  // Combine partials across the 16 n-segments (staged: 16 -> 8 -> 1).
  if (w < 8) {
#pragma unroll
    for (int ct = 0; ct < 4; ++ct)
#pragma unroll
      for (int mt = 0; mt < 2; ++mt)
#pragma unroll
        for (int r = 0; r < 4; ++r)
          Ot[(w * 64 + ct * 16 + quad * 4 + r) * 33 + mt * 16 + l15] =
              acc[ct][mt][r];
  }
  __syncthreads();
  if (w >= 8) {
#pragma unroll
    for (int ct = 0; ct < 4; ++ct)
#pragma unroll
      for (int mt = 0; mt < 2; ++mt)
#pragma unroll
        for (int r = 0; r < 4; ++r)
          Ot[((w - 8) * 64 + ct * 16 + quad * 4 + r) * 33 + mt * 16 + l15] +=
              acc[ct][mt][r];
  }
  __syncthreads();
  // 2048 outputs, 1024 threads -> 2 each; m consecutive across lanes.
  for (int idx = t; idx < 2048; idx += 1024) {
    int cc = idx >> 5, m = idx & 31;
    float v = 0.f;
#pragma unroll
    for (int s = 0; s < 8; ++s) v += Ot[(s * 64 + cc) * 33 + m];
    out[cc * N_TOK + m0 + m] = v + x[cc * N_TOK + m0 + m];
  }
}

// ---------------------------------------------------------------------------
extern "C" void kernel_launch(void* const* d_in, const int* in_sizes, int n_in,
                              void* d_out, int out_size, void* d_ws,
                              size_t ws_size, hipStream_t stream) {
  const float* x = (const float*)d_in[0];     // [64][8192]
  const float* W = (const float*)d_in[1];     // [32][64]
  const float* bias = (const float*)d_in[2];  // [32]
  float* out = (float*)d_out;                 // [64][8192]

  char* ws = (char*)d_ws;
  _Float16* qe = (_Float16*)ws;                 // 8192*32*2 = 512 KB
  _Float16* vht = (_Float16*)(ws + 524288);     // blocked vh: 1 MB
  float* Bn = (float*)(ws + 524288 + 1048576);  // 8192*4 = 32 KB

  prep_kernel<<<1536, 256, 0, stream>>>(x, W, bias, qe, vht);
  pass1_kernel<<<256, 1024, 0, stream>>>(qe, Bn);
  pass2_kernel<<<256, 1024, 0, stream>>>(qe, vht, Bn, x, out);
}